// Round 2
// baseline (195.113 us; speedup 1.0000x reference)
//
#include <hip/hip_runtime.h>

#define N_ROWS 32768
#define DIM    2048
#define KSEL   1638
#define MPAD   1664   // KSEL padded to multiple of 128
#define ZHALF  16384  // out rows zeroed per GEMM kernel
#define ZROWS  40     // out-rows zeroed per zero-role block
#define GTILES 416    // 13 x 32 gemm tiles

typedef __attribute__((ext_vector_type(4))) float          f32x4;
typedef __attribute__((ext_vector_type(4))) unsigned short us4;
typedef __attribute__((ext_vector_type(8))) unsigned short us8;
typedef __bf16 bf16x8 __attribute__((ext_vector_type(8)));

__device__ __forceinline__ unsigned short f2bf(float f) {
    unsigned u = __float_as_uint(f);
    u += 0x7FFFu + ((u >> 16) & 1u);   // RNE
    return (unsigned short)(u >> 16);
}

__device__ __forceinline__ void gload_lds16(const void* g, void* l) {
    __builtin_amdgcn_global_load_lds(
        (const __attribute__((address_space(1))) unsigned int*)(uintptr_t)g,
        (__attribute__((address_space(3))) unsigned int*)(uintptr_t)l, 16, 0, 0);
}

// ---------------- prep: gate dot-products + W transpose/convert + mask zero
// Harness re-poisons the out allocation every iteration (fill dispatch,
// 1.07 GB, once per iter), so the full 268 MB out-zero is mandatory.
// prep keeps the gate as a pure read stream; the out-zero lives in the
// GEMMs as dedicated streaming blocks (see gemm_k) where it overlaps MFMA.
// Block partition: [0,8192) gate (4 rows each), [8192,10240) convt,
// [10240,10272) mask zeroing (unconditional -- poison-safe).
__global__ __launch_bounds__(256) void prep_k(const float* __restrict__ x,
                                              const float* __restrict__ Wg,
                                              const float* __restrict__ bg,
                                              float* __restrict__ scores,
                                              const float* __restrict__ W1,
                                              const float* __restrict__ W2,
                                              unsigned short* __restrict__ W1t,
                                              unsigned short* __restrict__ W2t,
                                              float* __restrict__ mask) {
    __shared__ unsigned short tile[64][72];   // +8 pad: conflict-free transpose
    const int b = blockIdx.x;
    const int t = threadIdx.x;
    if (b < 8192) {
        // ---- gate: one wave per row, 4 rows per block, pure streaming ----
        const int lane = t & 63, wid = t >> 6;
        const int row = b * 4 + wid;
        const float* xr = x + (size_t)row * DIM;
        float acc = 0.f;
#pragma unroll
        for (int i = 0; i < 8; ++i) {
            const int c = i * 256 + lane * 4;
            f32x4 a = __builtin_nontemporal_load((const f32x4*)&xr[c]);
            f32x4 w = *(const f32x4*)&Wg[c];
#pragma unroll
            for (int j = 0; j < 4; ++j) acc = fmaf(a[j], w[j], acc);
        }
#pragma unroll
        for (int off = 32; off >= 1; off >>= 1) acc += __shfl_down(acc, off);
        if (lane == 0) scores[row] = acc + bg[0];
    } else if (b < 8192 + 2048) {
        // ---- convert + transpose W (f32 [k][n] -> bf16 [n][k]) ----
        const int cb = b - 8192;
        const int z = cb >> 10;            // 0: W1, 1: W2
        const int rem = cb & 1023;
        const int k0 = (rem & 31) * 64;
        const int n0 = (rem >> 5) * 64;
        const float* W = z ? W2 : W1;
        unsigned short* Wt = z ? W2t : W1t;
        {
            const int r = t >> 4, c = (t & 15) * 4;
#pragma unroll
            for (int p = 0; p < 4; ++p) {
                const int rr = p * 16 + r;
                f32x4 v = *(const f32x4*)&W[(size_t)(k0 + rr) * DIM + n0 + c];
#pragma unroll
                for (int j = 0; j < 4; ++j) tile[rr][c + j] = f2bf(v[j]);
            }
        }
        __syncthreads();
        {
            const int n = t >> 4, kk = (t & 15) * 4;
#pragma unroll
            for (int p = 0; p < 4; ++p) {
                const int nn = p * 16 + n;
                us4 o;
#pragma unroll
                for (int j = 0; j < 4; ++j) o[j] = tile[kk + j][nn];
                *(us4*)&Wt[(size_t)(n0 + nn) * DIM + k0 + kk] = o;
            }
        }
    } else {
        // ---- zero mask: 32 blocks x 256 thr x 16 B = 128 KiB ----
        const int mb = b - (8192 + 2048);
        const f32x4 zf = {};
        __builtin_nontemporal_store(zf, (f32x4*)&mask[(size_t)mb * 1024 + t * 4]);
    }
}

// ---------------- top-K select (single block, keys in registers) ------
__global__ __launch_bounds__(1024) void select_k(const float* __restrict__ scores,
                                                 int* __restrict__ sel) {
    const int t = threadIdx.x;
    const int lane = t & 63, wid = t >> 6;
    unsigned key[32];
    unsigned kmin = 0xFFFFFFFFu, kmax = 0u;
#pragma unroll
    for (int i = 0; i < 8; ++i) {
        f32x4 v = *(const f32x4*)&scores[t * 32 + i * 4];
#pragma unroll
        for (int j = 0; j < 4; ++j) {
            unsigned u = __float_as_uint(v[j]);
            u = (u & 0x80000000u) ? ~u : (u | 0x80000000u);
            key[i * 4 + j] = u;
            kmin = min(kmin, u);
            kmax = max(kmax, u);
        }
    }
#pragma unroll
    for (int off = 32; off >= 1; off >>= 1) {
        kmin = min(kmin, (unsigned)__shfl_down((int)kmin, off));
        kmax = max(kmax, (unsigned)__shfl_down((int)kmax, off));
    }
    __shared__ unsigned wmin[16], wmax[16];
    __shared__ unsigned cnt[40];
    __shared__ unsigned gmin, gmax;
    if (t < 40) cnt[t] = 0u;
    if (lane == 0) { wmin[wid] = kmin; wmax[wid] = kmax; }
    __syncthreads();
    if (t == 0) {
        unsigned mn = wmin[0], mx = wmax[0];
        for (int w = 1; w < 16; ++w) { mn = min(mn, wmin[w]); mx = max(mx, wmax[w]); }
        gmin = mn; gmax = mx;
    }
    __syncthreads();
    unsigned lo = gmin, hi = gmax;
    int it = 0;
    while (lo < hi) {
        const unsigned mid = (unsigned)(((unsigned long long)lo + hi + 1ull) >> 1);
        int c = 0;
#pragma unroll
        for (int i = 0; i < 32; ++i) c += (key[i] >= mid) ? 1 : 0;
#pragma unroll
        for (int off = 32; off >= 1; off >>= 1) c += __shfl_down(c, off);
        if (lane == 0) atomicAdd(&cnt[it], (unsigned)c);
        __syncthreads();
        const unsigned total = cnt[it];
        if (total >= (unsigned)KSEL) lo = mid; else hi = mid - 1;
        ++it;   // fresh counter slot each iter -> one barrier per iter
    }
    const unsigned kv = lo;   // K-th largest key
    __shared__ unsigned ctr, ectr;
    __shared__ int eq[256];
    if (t == 0) { ctr = 0; ectr = 0; }
    __syncthreads();
#pragma unroll
    for (int i = 0; i < 32; ++i) {
        const unsigned k = key[i];
        if (k > kv) {
            unsigned p = atomicAdd(&ctr, 1u);
            sel[p] = t * 32 + i;
        } else if (k == kv) {
            unsigned p = atomicAdd(&ectr, 1u);
            if (p < 256u) eq[p] = t * 32 + i;
        }
    }
    __syncthreads();
    if (t == 0) {   // ties at kv: take smallest indices (lax.top_k stability)
        const int C = (int)ctr;
        const int R = KSEL - C;
        const int E = (int)(ectr < 256u ? ectr : 256u);
        for (int r = 0; r < R; ++r) {
            int mi = r;
            for (int j = r + 1; j < E; ++j)
                if (eq[j] < eq[mi]) mi = j;
            int tmp = eq[r]; eq[r] = eq[mi]; eq[mi] = tmp;
            sel[C + r] = eq[r];
        }
    }
}

// ---------------- gather active rows -> bf16 A, write mask ------------
__global__ __launch_bounds__(256) void gather_k(const float* __restrict__ x,
                                                const int* __restrict__ sel,
                                                unsigned short* __restrict__ Abf,
                                                float* __restrict__ mask) {
    const int b = blockIdx.x, t = threadIdx.x;
    unsigned short* dst = Abf + (size_t)b * DIM + t * 8;
    if (b < KSEL) {
        const int src = sel[b];
        if (t == 0) mask[src] = 1.0f;
        const float* xr = x + (size_t)src * DIM + t * 8;
        f32x4 v0 = *(const f32x4*)xr;
        f32x4 v1 = *(const f32x4*)(xr + 4);
        us8 o;
#pragma unroll
        for (int j = 0; j < 4; ++j) { o[j] = f2bf(v0[j]); o[j + 4] = f2bf(v1[j]); }
        *(us8*)dst = o;
    } else {
        us8 z = {};
        *(us8*)dst = z;   // zero pad rows so GEMM tiles are full
    }
}

// ---------------- GEMM: C[MPAD x DIM] = A[MPAD x DIM] * Bt^T ----------
// 128x64 tile, BK=32, 4 waves (2Mx2N, 64x32 each), 16x16x32 bf16 MFMA.
// Fused zero-streaming: ODD blocks are dedicated out-zeroing blocks (no
// barriers, no LDS traffic, pure nontemporal stores) interleaved with the
// EVEN compute blocks so every CU holds a mix -- the store stream retires
// asynchronously under the MFMA pipe (m114 co-schedule). This replaces the
// R1 in-K-loop stores, which serialized into the per-iteration vmcnt(0)
// barrier drain (stores count against vmcnt -> +store-latency x 64 iters).
// Zero blocks are mask-checked: selected rows are untouched; gemm<1>'s
// scatter is their sole writer -> race-free.
// EPI=0: H = relu(A*W1 + b1) -> bf16, zero blocks cover rows [0, ZHALF).
// EPI=1: scatter f32 rows of A*W2+b2, zero blocks cover [ZHALF, N).
template <int EPI>
__global__ __launch_bounds__(256, 2) void gemm_k(const unsigned short* __restrict__ A,
                                                 const unsigned short* __restrict__ Bt,
                                                 const float* __restrict__ bias,
                                                 unsigned short* __restrict__ Hout,
                                                 float* __restrict__ Cout,
                                                 const int* __restrict__ sel,
                                                 const float* __restrict__ mask,
                                                 float* __restrict__ zout) {
    __shared__ unsigned short lA[2][128 * 32];
    __shared__ unsigned short lB[2][64 * 32];
    const int bid = blockIdx.x;
    const int t = threadIdx.x;

    if (bid & 1) {
        // ---- zero-stream role ----
        const int zb = bid >> 1;
        const int lane = t & 63;
        const int base = zb * ZROWS;
        const int zrow0 = (EPI ? ZHALF : 0) + base;
        float mv = 1.0f;   // 1.0 -> skip
        if (lane < ZROWS && base + lane < ZHALF) mv = mask[zrow0 + lane];
        const f32x4 zf = {};
        for (int r = 0; r < ZROWS; ++r) {
            if (base + r >= ZHALF) break;
            const float m = __shfl(mv, r);           // wave-uniform
            if (__float_as_uint(m) == 0u) {
                f32x4* p = (f32x4*)(zout + (size_t)(zrow0 + r) * DIM) + t;
                __builtin_nontemporal_store(zf, p);
                __builtin_nontemporal_store(zf, p + 256);
            }
        }
        return;
    }

    const int g = bid >> 1;
    const int lane = t & 63;
    const int wid = t >> 6;
    const int m0 = (g % 13) * 128;
    const int n0 = (g / 13) * 64;
    const int wm = (wid >> 1) * 64;
    const int wn = (wid & 1) * 32;

    f32x4 acc[4][2] = {};

    const int e0 = t, e1 = t + 256;
    const unsigned short* gA0 = A + (size_t)(m0 + (e0 >> 2)) * DIM + (e0 & 3) * 8;
    const unsigned short* gA1 = A + (size_t)(m0 + (e1 >> 2)) * DIM + (e1 & 3) * 8;
    const unsigned short* gB0 = Bt + (size_t)(n0 + (t >> 2)) * DIM + (t & 3) * 8;
    const int lo0 = e0 * 8, lo1 = e1 * 8, lob = t * 8;

    const int aoff = (wm + (lane & 15)) * 32 + (lane >> 4) * 8;
    const int boff = (wn + (lane & 15)) * 32 + (lane >> 4) * 8;

    // prologue: stage k=0 into buf 0
    gload_lds16(gA0, &lA[0][lo0]);
    gload_lds16(gA1, &lA[0][lo1]);
    gload_lds16(gB0, &lB[0][lob]);
    __syncthreads();

    int cur = 0;
    for (int k0 = 0; k0 < DIM; k0 += 32) {
        if (k0 + 32 < DIM) {   // issue next tile's loads before compute
            const int nxt = cur ^ 1, kn = k0 + 32;
            gload_lds16(gA0 + kn, &lA[nxt][lo0]);
            gload_lds16(gA1 + kn, &lA[nxt][lo1]);
            gload_lds16(gB0 + kn, &lB[nxt][lob]);
        }
        bf16x8 af[4], bfr[2];
#pragma unroll
        for (int mf = 0; mf < 4; ++mf)
            af[mf] = *(const bf16x8*)&lA[cur][aoff + mf * 16 * 32];
#pragma unroll
        for (int nf = 0; nf < 2; ++nf)
            bfr[nf] = *(const bf16x8*)&lB[cur][boff + nf * 16 * 32];
#pragma unroll
        for (int mf = 0; mf < 4; ++mf)
#pragma unroll
            for (int nf = 0; nf < 2; ++nf)
                acc[mf][nf] = __builtin_amdgcn_mfma_f32_16x16x32_bf16(
                    af[mf], bfr[nf], acc[mf][nf], 0, 0, 0);
        __syncthreads();   // drains vmcnt(0): next buffer ready, prev reads done
        cur ^= 1;
    }

#pragma unroll
    for (int mf = 0; mf < 4; ++mf) {
        const int rbase = m0 + wm + mf * 16 + (lane >> 4) * 4;
#pragma unroll
        for (int nf = 0; nf < 2; ++nf) {
            const int col = n0 + wn + nf * 16 + (lane & 15);
            const float bv = bias[col];
            if (EPI == 0) {
#pragma unroll
                for (int j = 0; j < 4; ++j) {
                    float v = acc[mf][nf][j] + bv;
                    v = fmaxf(v, 0.f);
                    Hout[(size_t)(rbase + j) * DIM + col] = f2bf(v);
                }
            } else {
#pragma unroll
                for (int j = 0; j < 4; ++j) {
                    const int r = rbase + j;
                    if (r < KSEL) {
                        __builtin_nontemporal_store(
                            acc[mf][nf][j] + bv,
                            &Cout[(size_t)sel[r] * DIM + col]);
                    }
                }
            }
        }
    }
}

extern "C" void kernel_launch(void* const* d_in, const int* in_sizes, int n_in,
                              void* d_out, int out_size, void* d_ws, size_t ws_size,
                              hipStream_t stream) {
    const float* x  = (const float*)d_in[0];
    const float* W1 = (const float*)d_in[1];
    const float* b1 = (const float*)d_in[2];
    const float* W2 = (const float*)d_in[3];
    const float* b2 = (const float*)d_in[4];
    const float* Wg = (const float*)d_in[5];
    const float* bg = (const float*)d_in[6];
    float* out  = (float*)d_out;
    float* mask = out + (size_t)N_ROWS * DIM;

    char* w = (char*)d_ws;
    float* scores = (float*)w;           w += (size_t)N_ROWS * 4;
    int* sel = (int*)w;                  w += 2048 * 4;
    unsigned short* Abf = (unsigned short*)w;  w += (size_t)MPAD * DIM * 2;
    unsigned short* Hbf = (unsigned short*)w;  w += (size_t)MPAD * DIM * 2;
    unsigned short* W1t = (unsigned short*)w;  w += (size_t)DIM * DIM * 2;
    unsigned short* W2t = (unsigned short*)w;  w += (size_t)DIM * DIM * 2;

    // gate + convt + mask-zero fused (gate no longer touches out/mask)
    hipLaunchKernelGGL(prep_k, dim3(8192 + 2048 + 32), dim3(256), 0, stream,
                       x, Wg, bg, scores, W1, W2, W1t, W2t, mask);
    hipLaunchKernelGGL(select_k, dim3(1), dim3(1024), 0, stream, scores, sel);
    hipLaunchKernelGGL(gather_k, dim3(MPAD), dim3(256), 0, stream, x, sel, Abf, mask);
    // interleaved compute/zero roles: even blocks gemm, odd blocks stream
    // zeros into out ([0,ZHALF) under gemm0, [ZHALF,N) under gemm1)
    hipLaunchKernelGGL((gemm_k<0>), dim3(2 * GTILES), dim3(256), 0, stream,
                       Abf, W1t, b1, Hbf, (float*)nullptr, (const int*)nullptr,
                       mask, out);
    hipLaunchKernelGGL((gemm_k<1>), dim3(2 * GTILES), dim3(256), 0, stream,
                       Hbf, W2t, b2, (unsigned short*)nullptr, out, sel,
                       mask, out);
}

// Round 3
// 168.258 us; speedup vs baseline: 1.1596x; 1.1596x over previous
//
#include <hip/hip_runtime.h>

#define N_ROWS 32768
#define DIM    2048
#define KSEL   1638
#define MPAD   1664   // KSEL padded to multiple of 128

typedef __attribute__((ext_vector_type(4))) float          f32x4;
typedef __attribute__((ext_vector_type(4))) unsigned short us4;
typedef __attribute__((ext_vector_type(8))) unsigned short us8;
typedef __bf16 bf16x8 __attribute__((ext_vector_type(8)));

__device__ __forceinline__ unsigned short f2bf(float f) {
    unsigned u = __float_as_uint(f);
    u += 0x7FFFu + ((u >> 16) & 1u);   // RNE
    return (unsigned short)(u >> 16);
}

__device__ __forceinline__ void gload_lds16(const void* g, void* l) {
    __builtin_amdgcn_global_load_lds(
        (const __attribute__((address_space(1))) unsigned int*)(uintptr_t)g,
        (__attribute__((address_space(3))) unsigned int*)(uintptr_t)l, 16, 0, 0);
}

// ---------------- prep: gate dot-products + W transpose/convert -------
// Pure read streams (268 MB x + 50 MB W); the mandatory 268 MB out-zero
// (harness re-poisons out every iteration) lives in selzero_k, where it
// overlaps the otherwise GPU-idle single-block top-K select.
// R1/R2 lesson: do NOT put the zero stream in/alongside the GEMMs -- it
// either serializes into the per-iter vmcnt(0) drain (R1, +7us) or
// displaces the 2nd compute block per CU that hides it (R2, +22us).
__global__ __launch_bounds__(256) void prep_k(const float* __restrict__ x,
                                              const float* __restrict__ Wg,
                                              const float* __restrict__ bg,
                                              float* __restrict__ scores,
                                              const float* __restrict__ W1,
                                              const float* __restrict__ W2,
                                              unsigned short* __restrict__ W1t,
                                              unsigned short* __restrict__ W2t) {
    __shared__ unsigned short tile[64][72];   // +8 pad: conflict-free transpose
    const int b = blockIdx.x;
    const int t = threadIdx.x;
    if (b < 8192) {
        // ---- gate: one wave per row, 4 rows per block, pure streaming ----
        const int lane = t & 63, wid = t >> 6;
        const int row = b * 4 + wid;
        const float* xr = x + (size_t)row * DIM;
        float acc = 0.f;
#pragma unroll
        for (int i = 0; i < 8; ++i) {
            const int c = i * 256 + lane * 4;
            f32x4 a = __builtin_nontemporal_load((const f32x4*)&xr[c]);
            f32x4 w = *(const f32x4*)&Wg[c];
#pragma unroll
            for (int j = 0; j < 4; ++j) acc = fmaf(a[j], w[j], acc);
        }
#pragma unroll
        for (int off = 32; off >= 1; off >>= 1) acc += __shfl_down(acc, off);
        if (lane == 0) scores[row] = acc + bg[0];
    } else {
        // ---- convert + transpose W (f32 [k][n] -> bf16 [n][k]) ----
        const int cb = b - 8192;
        const int z = cb >> 10;            // 0: W1, 1: W2
        const int rem = cb & 1023;
        const int k0 = (rem & 31) * 64;
        const int n0 = (rem >> 5) * 64;
        const float* W = z ? W2 : W1;
        unsigned short* Wt = z ? W2t : W1t;
        {
            const int r = t >> 4, c = (t & 15) * 4;
#pragma unroll
            for (int p = 0; p < 4; ++p) {
                const int rr = p * 16 + r;
                f32x4 v = *(const f32x4*)&W[(size_t)(k0 + rr) * DIM + n0 + c];
#pragma unroll
                for (int j = 0; j < 4; ++j) tile[rr][c + j] = f2bf(v[j]);
            }
        }
        __syncthreads();
        {
            const int n = t >> 4, kk = (t & 15) * 4;
#pragma unroll
            for (int p = 0; p < 4; ++p) {
                const int nn = p * 16 + n;
                us4 o;
#pragma unroll
                for (int j = 0; j < 4; ++j) o[j] = tile[kk + j][nn];
                *(us4*)&Wt[(size_t)(n0 + nn) * DIM + k0 + kk] = o;
            }
        }
    }
}

// ---------------- top-K select (block 0) + full out/mask zero ---------
// Block 0 runs the single-block radix/bisection select (~11 us) while
// blocks 1..2049 stream 268.57 MB of zeros over out+mask (~40 us across
// the otherwise idle GPU). Unconditional zeroing: gemm_k<1>'s scatter
// (a later kernel) overwrites the KSEL selected rows; gather_k sets
// mask[sel]=1. out_size = 32768*2049*4 B = 2049 blocks x 1024 thr x 8
// f32x4 exactly.
__global__ __launch_bounds__(1024) void selzero_k(const float* __restrict__ scores,
                                                  int* __restrict__ sel,
                                                  float* __restrict__ outbuf) {
    const int t = threadIdx.x;
    if (blockIdx.x > 0) {
        // ---- zero-stream role: 128 KiB per block ----
        const f32x4 zf = {};
        f32x4* p = (f32x4*)outbuf + (size_t)(blockIdx.x - 1) * 8192 + t;
#pragma unroll
        for (int r = 0; r < 8; ++r)
            __builtin_nontemporal_store(zf, p + r * 1024);
        return;
    }
    const int lane = t & 63, wid = t >> 6;
    unsigned key[32];
    unsigned kmin = 0xFFFFFFFFu, kmax = 0u;
#pragma unroll
    for (int i = 0; i < 8; ++i) {
        f32x4 v = *(const f32x4*)&scores[t * 32 + i * 4];
#pragma unroll
        for (int j = 0; j < 4; ++j) {
            unsigned u = __float_as_uint(v[j]);
            u = (u & 0x80000000u) ? ~u : (u | 0x80000000u);
            key[i * 4 + j] = u;
            kmin = min(kmin, u);
            kmax = max(kmax, u);
        }
    }
#pragma unroll
    for (int off = 32; off >= 1; off >>= 1) {
        kmin = min(kmin, (unsigned)__shfl_down((int)kmin, off));
        kmax = max(kmax, (unsigned)__shfl_down((int)kmax, off));
    }
    __shared__ unsigned wmin[16], wmax[16];
    __shared__ unsigned cnt[40];
    __shared__ unsigned gmin, gmax;
    if (t < 40) cnt[t] = 0u;
    if (lane == 0) { wmin[wid] = kmin; wmax[wid] = kmax; }
    __syncthreads();
    if (t == 0) {
        unsigned mn = wmin[0], mx = wmax[0];
        for (int w = 1; w < 16; ++w) { mn = min(mn, wmin[w]); mx = max(mx, wmax[w]); }
        gmin = mn; gmax = mx;
    }
    __syncthreads();
    unsigned lo = gmin, hi = gmax;
    int it = 0;
    while (lo < hi) {
        const unsigned mid = (unsigned)(((unsigned long long)lo + hi + 1ull) >> 1);
        int c = 0;
#pragma unroll
        for (int i = 0; i < 32; ++i) c += (key[i] >= mid) ? 1 : 0;
#pragma unroll
        for (int off = 32; off >= 1; off >>= 1) c += __shfl_down(c, off);
        if (lane == 0) atomicAdd(&cnt[it], (unsigned)c);
        __syncthreads();
        const unsigned total = cnt[it];
        if (total >= (unsigned)KSEL) lo = mid; else hi = mid - 1;
        ++it;   // fresh counter slot each iter -> one barrier per iter
    }
    const unsigned kv = lo;   // K-th largest key
    __shared__ unsigned ctr, ectr;
    __shared__ int eq[256];
    if (t == 0) { ctr = 0; ectr = 0; }
    __syncthreads();
#pragma unroll
    for (int i = 0; i < 32; ++i) {
        const unsigned k = key[i];
        if (k > kv) {
            unsigned p = atomicAdd(&ctr, 1u);
            sel[p] = t * 32 + i;
        } else if (k == kv) {
            unsigned p = atomicAdd(&ectr, 1u);
            if (p < 256u) eq[p] = t * 32 + i;
        }
    }
    __syncthreads();
    if (t == 0) {   // ties at kv: take smallest indices (lax.top_k stability)
        const int C = (int)ctr;
        const int R = KSEL - C;
        const int E = (int)(ectr < 256u ? ectr : 256u);
        for (int r = 0; r < R; ++r) {
            int mi = r;
            for (int j = r + 1; j < E; ++j)
                if (eq[j] < eq[mi]) mi = j;
            int tmp = eq[r]; eq[r] = eq[mi]; eq[mi] = tmp;
            sel[C + r] = eq[r];
        }
    }
}

// ---------------- gather active rows -> bf16 A, write mask ------------
__global__ __launch_bounds__(256) void gather_k(const float* __restrict__ x,
                                                const int* __restrict__ sel,
                                                unsigned short* __restrict__ Abf,
                                                float* __restrict__ mask) {
    const int b = blockIdx.x, t = threadIdx.x;
    unsigned short* dst = Abf + (size_t)b * DIM + t * 8;
    if (b < KSEL) {
        const int src = sel[b];
        if (t == 0) mask[src] = 1.0f;
        const float* xr = x + (size_t)src * DIM + t * 8;
        f32x4 v0 = *(const f32x4*)xr;
        f32x4 v1 = *(const f32x4*)(xr + 4);
        us8 o;
#pragma unroll
        for (int j = 0; j < 4; ++j) { o[j] = f2bf(v0[j]); o[j + 4] = f2bf(v1[j]); }
        *(us8*)dst = o;
    } else {
        us8 z = {};
        *(us8*)dst = z;   // zero pad rows so GEMM tiles are full
    }
}

// ---------------- GEMM: C[MPAD x DIM] = A[MPAD x DIM] * Bt^T ----------
// 128x64 tile, BK=32, 4 waves (2Mx2N, 64x32 each), 16x16x32 bf16 MFMA.
// 416 blocks -> 2 blocks/CU (launch_bounds(256,2), LDS 24 KB/block):
// the other block's MFMA hides this block's vmcnt(0) barrier drain
// (m114: MFMA+VALU co-schedule across waves works). Keep this kernel
// free of extra memory traffic (R1/R2 regressions).
// EPI=0: H = relu(A*W1 + b1) -> bf16.  EPI=1: scatter f32 rows of A*W2+b2.
template <int EPI>
__global__ __launch_bounds__(256, 2) void gemm_k(const unsigned short* __restrict__ A,
                                                 const unsigned short* __restrict__ Bt,
                                                 const float* __restrict__ bias,
                                                 unsigned short* __restrict__ Hout,
                                                 float* __restrict__ Cout,
                                                 const int* __restrict__ sel) {
    __shared__ unsigned short lA[2][128 * 32];
    __shared__ unsigned short lB[2][64 * 32];
    const int t = threadIdx.x;
    const int lane = t & 63;
    const int wid = t >> 6;
    const int m0 = blockIdx.x * 128;
    const int n0 = blockIdx.y * 64;
    const int wm = (wid >> 1) * 64;
    const int wn = (wid & 1) * 32;

    f32x4 acc[4][2] = {};

    const int e0 = t, e1 = t + 256;
    const unsigned short* gA0 = A + (size_t)(m0 + (e0 >> 2)) * DIM + (e0 & 3) * 8;
    const unsigned short* gA1 = A + (size_t)(m0 + (e1 >> 2)) * DIM + (e1 & 3) * 8;
    const unsigned short* gB0 = Bt + (size_t)(n0 + (t >> 2)) * DIM + (t & 3) * 8;
    const int lo0 = e0 * 8, lo1 = e1 * 8, lob = t * 8;

    const int aoff = (wm + (lane & 15)) * 32 + (lane >> 4) * 8;
    const int boff = (wn + (lane & 15)) * 32 + (lane >> 4) * 8;

    // prologue: stage k=0 into buf 0
    gload_lds16(gA0, &lA[0][lo0]);
    gload_lds16(gA1, &lA[0][lo1]);
    gload_lds16(gB0, &lB[0][lob]);
    __syncthreads();

    int cur = 0;
    for (int k0 = 0; k0 < DIM; k0 += 32) {
        if (k0 + 32 < DIM) {   // issue next tile's loads before compute
            const int nxt = cur ^ 1, kn = k0 + 32;
            gload_lds16(gA0 + kn, &lA[nxt][lo0]);
            gload_lds16(gA1 + kn, &lA[nxt][lo1]);
            gload_lds16(gB0 + kn, &lB[nxt][lob]);
        }
        bf16x8 af[4], bfr[2];
#pragma unroll
        for (int mf = 0; mf < 4; ++mf)
            af[mf] = *(const bf16x8*)&lA[cur][aoff + mf * 16 * 32];
#pragma unroll
        for (int nf = 0; nf < 2; ++nf)
            bfr[nf] = *(const bf16x8*)&lB[cur][boff + nf * 16 * 32];
#pragma unroll
        for (int mf = 0; mf < 4; ++mf)
#pragma unroll
            for (int nf = 0; nf < 2; ++nf)
                acc[mf][nf] = __builtin_amdgcn_mfma_f32_16x16x32_bf16(
                    af[mf], bfr[nf], acc[mf][nf], 0, 0, 0);
        __syncthreads();   // drains vmcnt(0): next buffer ready, prev reads done
        cur ^= 1;
    }

#pragma unroll
    for (int mf = 0; mf < 4; ++mf) {
        const int rbase = m0 + wm + mf * 16 + (lane >> 4) * 4;
#pragma unroll
        for (int nf = 0; nf < 2; ++nf) {
            const int col = n0 + wn + nf * 16 + (lane & 15);
            const float bv = bias[col];
            if (EPI == 0) {
#pragma unroll
                for (int j = 0; j < 4; ++j) {
                    float v = acc[mf][nf][j] + bv;
                    v = fmaxf(v, 0.f);
                    Hout[(size_t)(rbase + j) * DIM + col] = f2bf(v);
                }
            } else {
#pragma unroll
                for (int j = 0; j < 4; ++j) {
                    const int r = rbase + j;
                    if (r < KSEL) {
                        __builtin_nontemporal_store(
                            acc[mf][nf][j] + bv,
                            &Cout[(size_t)sel[r] * DIM + col]);
                    }
                }
            }
        }
    }
}

extern "C" void kernel_launch(void* const* d_in, const int* in_sizes, int n_in,
                              void* d_out, int out_size, void* d_ws, size_t ws_size,
                              hipStream_t stream) {
    const float* x  = (const float*)d_in[0];
    const float* W1 = (const float*)d_in[1];
    const float* b1 = (const float*)d_in[2];
    const float* W2 = (const float*)d_in[3];
    const float* b2 = (const float*)d_in[4];
    const float* Wg = (const float*)d_in[5];
    const float* bg = (const float*)d_in[6];
    float* out  = (float*)d_out;
    float* mask = out + (size_t)N_ROWS * DIM;

    char* w = (char*)d_ws;
    float* scores = (float*)w;           w += (size_t)N_ROWS * 4;
    int* sel = (int*)w;                  w += 2048 * 4;
    unsigned short* Abf = (unsigned short*)w;  w += (size_t)MPAD * DIM * 2;
    unsigned short* Hbf = (unsigned short*)w;  w += (size_t)MPAD * DIM * 2;
    unsigned short* W1t = (unsigned short*)w;  w += (size_t)DIM * DIM * 2;
    unsigned short* W2t = (unsigned short*)w;  w += (size_t)DIM * DIM * 2;

    // pure read streams: gate dot-products + W convert/transpose
    hipLaunchKernelGGL(prep_k, dim3(8192 + 2048), dim3(256), 0, stream,
                       x, Wg, bg, scores, W1, W2, W1t, W2t);
    // block 0: top-K select; blocks 1..2049: zero out+mask (268.57 MB)
    // over the otherwise idle GPU. Scatter later rewrites selected rows.
    hipLaunchKernelGGL(selzero_k, dim3(1 + 2049), dim3(1024), 0, stream,
                       scores, sel, out);
    hipLaunchKernelGGL(gather_k, dim3(MPAD), dim3(256), 0, stream, x, sel, Abf, mask);
    hipLaunchKernelGGL((gemm_k<0>), dim3(MPAD / 128, DIM / 64), dim3(256), 0, stream,
                       Abf, W1t, b1, Hbf, (float*)nullptr, (const int*)nullptr);
    hipLaunchKernelGGL((gemm_k<1>), dim3(MPAD / 128, DIM / 64), dim3(256), 0, stream,
                       Hbf, W2t, b2, (unsigned short*)nullptr, out, sel);
}

// Round 4
// 151.421 us; speedup vs baseline: 1.2885x; 1.1112x over previous
//
#include <hip/hip_runtime.h>

#define N_ROWS 32768
#define DIM    2048
#define KSEL   1638
#define MPAD   1664   // KSEL padded to multiple of 128

typedef __attribute__((ext_vector_type(4))) float          f32x4;
typedef __attribute__((ext_vector_type(4))) unsigned short us4;
typedef __attribute__((ext_vector_type(8))) unsigned short us8;
typedef __bf16 bf16x8 __attribute__((ext_vector_type(8)));

__device__ __forceinline__ unsigned short f2bf(float f) {
    unsigned u = __float_as_uint(f);
    u += 0x7FFFu + ((u >> 16) & 1u);   // RNE
    return (unsigned short)(u >> 16);
}

__device__ __forceinline__ void gload_lds16(const void* g, void* l) {
    __builtin_amdgcn_global_load_lds(
        (const __attribute__((address_space(1))) unsigned int*)(uintptr_t)g,
        (__attribute__((address_space(3))) unsigned int*)(uintptr_t)l, 16, 0, 0);
}

// ---------------- prep: gate dot-products + W transpose/convert -------
// Pure read streams (268 MB x + 50 MB W); the mandatory 268 MB out-zero
// (harness re-poisons out every iteration) lives in selzero_k, where it
// overlaps the otherwise GPU-idle single-block top-K select.
// Streaming phases are at the BW floor: prep+selzero ~= (335+269)/7TB/s.
__global__ __launch_bounds__(256) void prep_k(const float* __restrict__ x,
                                              const float* __restrict__ Wg,
                                              const float* __restrict__ bg,
                                              float* __restrict__ scores,
                                              const float* __restrict__ W1,
                                              const float* __restrict__ W2,
                                              unsigned short* __restrict__ W1t,
                                              unsigned short* __restrict__ W2t) {
    __shared__ unsigned short tile[64][72];   // +8 pad: conflict-free transpose
    const int b = blockIdx.x;
    const int t = threadIdx.x;
    if (b < 8192) {
        // ---- gate: one wave per row, 4 rows per block, pure streaming ----
        const int lane = t & 63, wid = t >> 6;
        const int row = b * 4 + wid;
        const float* xr = x + (size_t)row * DIM;
        float acc = 0.f;
#pragma unroll
        for (int i = 0; i < 8; ++i) {
            const int c = i * 256 + lane * 4;
            f32x4 a = __builtin_nontemporal_load((const f32x4*)&xr[c]);
            f32x4 w = *(const f32x4*)&Wg[c];
#pragma unroll
            for (int j = 0; j < 4; ++j) acc = fmaf(a[j], w[j], acc);
        }
#pragma unroll
        for (int off = 32; off >= 1; off >>= 1) acc += __shfl_down(acc, off);
        if (lane == 0) scores[row] = acc + bg[0];
    } else {
        // ---- convert + transpose W (f32 [k][n] -> bf16 [n][k]) ----
        const int cb = b - 8192;
        const int z = cb >> 10;            // 0: W1, 1: W2
        const int rem = cb & 1023;
        const int k0 = (rem & 31) * 64;
        const int n0 = (rem >> 5) * 64;
        const float* W = z ? W2 : W1;
        unsigned short* Wt = z ? W2t : W1t;
        {
            const int r = t >> 4, c = (t & 15) * 4;
#pragma unroll
            for (int p = 0; p < 4; ++p) {
                const int rr = p * 16 + r;
                f32x4 v = *(const f32x4*)&W[(size_t)(k0 + rr) * DIM + n0 + c];
#pragma unroll
                for (int j = 0; j < 4; ++j) tile[rr][c + j] = f2bf(v[j]);
            }
        }
        __syncthreads();
        {
            const int n = t >> 4, kk = (t & 15) * 4;
#pragma unroll
            for (int p = 0; p < 4; ++p) {
                const int nn = p * 16 + n;
                us4 o;
#pragma unroll
                for (int j = 0; j < 4; ++j) o[j] = tile[kk + j][nn];
                *(us4*)&Wt[(size_t)(n0 + nn) * DIM + k0 + kk] = o;
            }
        }
    }
}

// ---------------- top-K select (block 0) + full out/mask zero ---------
// Block 0 runs the single-block bisection select (~11 us) while blocks
// 1..2049 stream 268.57 MB of zeros over out+mask (~38 us across the
// otherwise idle GPU); select is fully hidden. Unconditional zeroing:
// gemm_k<1>'s scatter (later kernel) rewrites the KSEL selected rows.
__global__ __launch_bounds__(1024) void selzero_k(const float* __restrict__ scores,
                                                  int* __restrict__ sel,
                                                  float* __restrict__ outbuf) {
    const int t = threadIdx.x;
    if (blockIdx.x > 0) {
        // ---- zero-stream role: 128 KiB per block ----
        const f32x4 zf = {};
        f32x4* p = (f32x4*)outbuf + (size_t)(blockIdx.x - 1) * 8192 + t;
#pragma unroll
        for (int r = 0; r < 8; ++r)
            __builtin_nontemporal_store(zf, p + r * 1024);
        return;
    }
    const int lane = t & 63, wid = t >> 6;
    unsigned key[32];
    unsigned kmin = 0xFFFFFFFFu, kmax = 0u;
#pragma unroll
    for (int i = 0; i < 8; ++i) {
        f32x4 v = *(const f32x4*)&scores[t * 32 + i * 4];
#pragma unroll
        for (int j = 0; j < 4; ++j) {
            unsigned u = __float_as_uint(v[j]);
            u = (u & 0x80000000u) ? ~u : (u | 0x80000000u);
            key[i * 4 + j] = u;
            kmin = min(kmin, u);
            kmax = max(kmax, u);
        }
    }
#pragma unroll
    for (int off = 32; off >= 1; off >>= 1) {
        kmin = min(kmin, (unsigned)__shfl_down((int)kmin, off));
        kmax = max(kmax, (unsigned)__shfl_down((int)kmax, off));
    }
    __shared__ unsigned wmin[16], wmax[16];
    __shared__ unsigned cnt[40];
    __shared__ unsigned gmin, gmax;
    if (t < 40) cnt[t] = 0u;
    if (lane == 0) { wmin[wid] = kmin; wmax[wid] = kmax; }
    __syncthreads();
    if (t == 0) {
        unsigned mn = wmin[0], mx = wmax[0];
        for (int w = 1; w < 16; ++w) { mn = min(mn, wmin[w]); mx = max(mx, wmax[w]); }
        gmin = mn; gmax = mx;
    }
    __syncthreads();
    unsigned lo = gmin, hi = gmax;
    int it = 0;
    while (lo < hi) {
        const unsigned mid = (unsigned)(((unsigned long long)lo + hi + 1ull) >> 1);
        int c = 0;
#pragma unroll
        for (int i = 0; i < 32; ++i) c += (key[i] >= mid) ? 1 : 0;
#pragma unroll
        for (int off = 32; off >= 1; off >>= 1) c += __shfl_down(c, off);
        if (lane == 0) atomicAdd(&cnt[it], (unsigned)c);
        __syncthreads();
        const unsigned total = cnt[it];
        if (total >= (unsigned)KSEL) lo = mid; else hi = mid - 1;
        ++it;   // fresh counter slot each iter -> one barrier per iter
    }
    const unsigned kv = lo;   // K-th largest key
    __shared__ unsigned ctr, ectr;
    __shared__ int eq[256];
    if (t == 0) { ctr = 0; ectr = 0; }
    __syncthreads();
#pragma unroll
    for (int i = 0; i < 32; ++i) {
        const unsigned k = key[i];
        if (k > kv) {
            unsigned p = atomicAdd(&ctr, 1u);
            sel[p] = t * 32 + i;
        } else if (k == kv) {
            unsigned p = atomicAdd(&ectr, 1u);
            if (p < 256u) eq[p] = t * 32 + i;
        }
    }
    __syncthreads();
    if (t == 0) {   // ties at kv: take smallest indices (lax.top_k stability)
        const int C = (int)ctr;
        const int R = KSEL - C;
        const int E = (int)(ectr < 256u ? ectr : 256u);
        for (int r = 0; r < R; ++r) {
            int mi = r;
            for (int j = r + 1; j < E; ++j)
                if (eq[j] < eq[mi]) mi = j;
            int tmp = eq[r]; eq[r] = eq[mi]; eq[mi] = tmp;
            sel[C + r] = eq[r];
        }
    }
}

// ---------------- gather active rows -> bf16 A, write mask ------------
__global__ __launch_bounds__(256) void gather_k(const float* __restrict__ x,
                                                const int* __restrict__ sel,
                                                unsigned short* __restrict__ Abf,
                                                float* __restrict__ mask) {
    const int b = blockIdx.x, t = threadIdx.x;
    unsigned short* dst = Abf + (size_t)b * DIM + t * 8;
    if (b < KSEL) {
        const int src = sel[b];
        if (t == 0) mask[src] = 1.0f;
        const float* xr = x + (size_t)src * DIM + t * 8;
        f32x4 v0 = *(const f32x4*)xr;
        f32x4 v1 = *(const f32x4*)(xr + 4);
        us8 o;
#pragma unroll
        for (int j = 0; j < 4; ++j) { o[j] = f2bf(v0[j]); o[j + 4] = f2bf(v1[j]); }
        *(us8*)dst = o;
    } else {
        us8 z = {};
        *(us8*)dst = z;   // zero pad rows so GEMM tiles are full
    }
}

// ---------------- GEMM: C[MPAD x DIM] = A[MPAD x DIM] * Bt^T ----------
// 128x64 tile, BK=64 (was 32: halves the per-iter vmcnt(0) barrier-drain
// count, doubles MFMA per phase to 16/wave), 4 waves (2Mx2N, 64x32 each),
// 16x16x32 bf16 MFMA. LDS 48 KB/block -> still 2 blocks/CU so the other
// block's MFMA hides this block's barrier drain.
// LDS layout is XOR-swizzled BOTH-SIDES (rule 21): at BK=64 the row
// stride is 128 B -> unswizzled ds_read_b128 would be a 16-way bank
// conflict. Physical 16B-chunk p of row r holds logical chunk p^(r&7);
// staged by pre-swizzling the global SOURCE column (global_load_lds
// writes linearly), read back with the same XOR (r&7 == lane&7 for all
// fragments since wm/wn/mf*16/nf*16 are 0 mod 8) -> 2-way (free).
// Bijective XCD swizzle: 416 = 8x52; each XCD gets 52 consecutive tiles
// spanning 4 B-panels = 1 MB -> B stays L2-resident per XCD.
// EPI=0: H = relu(A*W1 + b1) -> bf16.  EPI=1: scatter f32 rows of A*W2+b2.
template <int EPI>
__global__ __launch_bounds__(256, 2) void gemm_k(const unsigned short* __restrict__ A,
                                                 const unsigned short* __restrict__ Bt,
                                                 const float* __restrict__ bias,
                                                 unsigned short* __restrict__ Hout,
                                                 float* __restrict__ Cout,
                                                 const int* __restrict__ sel) {
    __shared__ unsigned short lA[2][128 * 64];
    __shared__ unsigned short lB[2][64 * 64];
    const int t = threadIdx.x;
    const int lane = t & 63;
    const int wid = t >> 6;
    const int swz = (blockIdx.x & 7) * 52 + (blockIdx.x >> 3);
    const int m0 = (swz % 13) * 128;
    const int n0 = (swz / 13) * 64;
    const int wm = (wid >> 1) * 64;
    const int wn = (wid & 1) * 32;

    f32x4 acc[4][2] = {};

    // staging: A tile 128x64 = 1024 16B chunks (4/thread), B 64x64 = 512 (2/thread)
    const unsigned short *gA[4], *gB[2];
    int la[4], lb[2];
#pragma unroll
    for (int i = 0; i < 4; ++i) {
        const int e = t + i * 256, r = e >> 3;
        gA[i] = A + (size_t)(m0 + r) * DIM + ((e & 7) ^ (r & 7)) * 8;
        la[i] = e * 8;
    }
#pragma unroll
    for (int i = 0; i < 2; ++i) {
        const int e = t + i * 256, r = e >> 3;
        gB[i] = Bt + (size_t)(n0 + r) * DIM + ((e & 7) ^ (r & 7)) * 8;
        lb[i] = e * 8;
    }

    // fragment read offsets (shorts); physical chunk = logical ^ (lane&7)
    const int pc0 = (((lane >> 4) + 0) ^ (lane & 7)) * 8;
    const int pc1 = (((lane >> 4) + 4) ^ (lane & 7)) * 8;
    const int aob = (wm + (lane & 15)) * 64;
    const int bob = (wn + (lane & 15)) * 64;

    // prologue: stage k=0 into buf 0
#pragma unroll
    for (int i = 0; i < 4; ++i) gload_lds16(gA[i], &lA[0][la[i]]);
#pragma unroll
    for (int i = 0; i < 2; ++i) gload_lds16(gB[i], &lB[0][lb[i]]);
    __syncthreads();

    int cur = 0;
    for (int k0 = 0; k0 < DIM; k0 += 64) {
        if (k0 + 64 < DIM) {   // issue next tile's loads before compute
            const int nxt = cur ^ 1, kn = k0 + 64;
#pragma unroll
            for (int i = 0; i < 4; ++i) gload_lds16(gA[i] + kn, &lA[nxt][la[i]]);
#pragma unroll
            for (int i = 0; i < 2; ++i) gload_lds16(gB[i] + kn, &lB[nxt][lb[i]]);
        }
        bf16x8 af0[4], af1[4], bf0[2], bf1[2];
#pragma unroll
        for (int mf = 0; mf < 4; ++mf) {
            af0[mf] = *(const bf16x8*)&lA[cur][aob + mf * 1024 + pc0];
            af1[mf] = *(const bf16x8*)&lA[cur][aob + mf * 1024 + pc1];
        }
#pragma unroll
        for (int nf = 0; nf < 2; ++nf) {
            bf0[nf] = *(const bf16x8*)&lB[cur][bob + nf * 1024 + pc0];
            bf1[nf] = *(const bf16x8*)&lB[cur][bob + nf * 1024 + pc1];
        }
#pragma unroll
        for (int mf = 0; mf < 4; ++mf)
#pragma unroll
            for (int nf = 0; nf < 2; ++nf)
                acc[mf][nf] = __builtin_amdgcn_mfma_f32_16x16x32_bf16(
                    af0[mf], bf0[nf], acc[mf][nf], 0, 0, 0);
#pragma unroll
        for (int mf = 0; mf < 4; ++mf)
#pragma unroll
            for (int nf = 0; nf < 2; ++nf)
                acc[mf][nf] = __builtin_amdgcn_mfma_f32_16x16x32_bf16(
                    af1[mf], bf1[nf], acc[mf][nf], 0, 0, 0);
        __syncthreads();   // drains vmcnt(0): next buffer ready, prev reads done
        cur ^= 1;
    }

#pragma unroll
    for (int mf = 0; mf < 4; ++mf) {
        const int rbase = m0 + wm + mf * 16 + (lane >> 4) * 4;
#pragma unroll
        for (int nf = 0; nf < 2; ++nf) {
            const int col = n0 + wn + nf * 16 + (lane & 15);
            const float bv = bias[col];
            if (EPI == 0) {
#pragma unroll
                for (int j = 0; j < 4; ++j) {
                    float v = acc[mf][nf][j] + bv;
                    v = fmaxf(v, 0.f);
                    Hout[(size_t)(rbase + j) * DIM + col] = f2bf(v);
                }
            } else {
#pragma unroll
                for (int j = 0; j < 4; ++j) {
                    const int r = rbase + j;
                    if (r < KSEL) {
                        __builtin_nontemporal_store(
                            acc[mf][nf][j] + bv,
                            &Cout[(size_t)sel[r] * DIM + col]);
                    }
                }
            }
        }
    }
}

extern "C" void kernel_launch(void* const* d_in, const int* in_sizes, int n_in,
                              void* d_out, int out_size, void* d_ws, size_t ws_size,
                              hipStream_t stream) {
    const float* x  = (const float*)d_in[0];
    const float* W1 = (const float*)d_in[1];
    const float* b1 = (const float*)d_in[2];
    const float* W2 = (const float*)d_in[3];
    const float* b2 = (const float*)d_in[4];
    const float* Wg = (const float*)d_in[5];
    const float* bg = (const float*)d_in[6];
    float* out  = (float*)d_out;
    float* mask = out + (size_t)N_ROWS * DIM;

    char* w = (char*)d_ws;
    float* scores = (float*)w;           w += (size_t)N_ROWS * 4;
    int* sel = (int*)w;                  w += 2048 * 4;
    unsigned short* Abf = (unsigned short*)w;  w += (size_t)MPAD * DIM * 2;
    unsigned short* Hbf = (unsigned short*)w;  w += (size_t)MPAD * DIM * 2;
    unsigned short* W1t = (unsigned short*)w;  w += (size_t)DIM * DIM * 2;
    unsigned short* W2t = (unsigned short*)w;  w += (size_t)DIM * DIM * 2;

    // pure read streams: gate dot-products + W convert/transpose
    hipLaunchKernelGGL(prep_k, dim3(8192 + 2048), dim3(256), 0, stream,
                       x, Wg, bg, scores, W1, W2, W1t, W2t);
    // block 0: top-K select; blocks 1..2049: zero out+mask (268.57 MB)
    hipLaunchKernelGGL(selzero_k, dim3(1 + 2049), dim3(1024), 0, stream,
                       scores, sel, out);
    hipLaunchKernelGGL(gather_k, dim3(MPAD), dim3(256), 0, stream, x, sel, Abf, mask);
    hipLaunchKernelGGL((gemm_k<0>), dim3(416), dim3(256), 0, stream,
                       Abf, W1t, b1, Hbf, (float*)nullptr, (const int*)nullptr);
    hipLaunchKernelGGL((gemm_k<1>), dim3(416), dim3(256), 0, stream,
                       Hbf, W2t, b2, (unsigned short*)nullptr, out, sel);
}

// Round 5
// 148.486 us; speedup vs baseline: 1.3140x; 1.0198x over previous
//
#include <hip/hip_runtime.h>

#define N_ROWS 32768
#define DIM    2048
#define KSEL   1638
#define MPAD   1664   // KSEL padded to multiple of 128
#define SELZR  12288  // out rows zeroed in selzero_k  (768 blocks x 16 rows)
#define G0ZR   22528  // gemm0 tail zeroes [SELZR, G0ZR)   (unconditional)
                      // gemm1 tail zeroes [G0ZR, N_ROWS)  (mask-conditional)
#define GTILE  416    // 13 x 32 gemm tiles
#define ZTAIL  320    // tail zero blocks per gemm (320 x 32 rows = 10240)

typedef __attribute__((ext_vector_type(4))) float          f32x4;
typedef __attribute__((ext_vector_type(4))) unsigned short us4;
typedef __attribute__((ext_vector_type(8))) unsigned short us8;
typedef __bf16 bf16x8 __attribute__((ext_vector_type(8)));

__device__ __forceinline__ unsigned short f2bf(float f) {
    unsigned u = __float_as_uint(f);
    u += 0x7FFFu + ((u >> 16) & 1u);   // RNE
    return (unsigned short)(u >> 16);
}

__device__ __forceinline__ void gload_lds16(const void* g, void* l) {
    __builtin_amdgcn_global_load_lds(
        (const __attribute__((address_space(1))) unsigned int*)(uintptr_t)g,
        (__attribute__((address_space(3))) unsigned int*)(uintptr_t)l, 16, 0, 0);
}

// ---------------- prep: gate dot-products + W transpose/convert -------
// Pure read streams (268 MB x + 50 MB W). The mandatory 268 MB out-zero
// (harness re-poisons out every iteration) is split three ways:
// 100 MB in selzero_k (hides the single-block select), 84 MB in each
// GEMM's tail-appended zero blocks (hides under the MFMA window's spare
// BW). R2 lesson: tail-APPEND zero blocks (gemm blocks own the first
// grid slots -> full residency); never interleave.
__global__ __launch_bounds__(256) void prep_k(const float* __restrict__ x,
                                              const float* __restrict__ Wg,
                                              const float* __restrict__ bg,
                                              float* __restrict__ scores,
                                              const float* __restrict__ W1,
                                              const float* __restrict__ W2,
                                              unsigned short* __restrict__ W1t,
                                              unsigned short* __restrict__ W2t) {
    __shared__ unsigned short tile[64][72];   // +8 pad: conflict-free transpose
    const int b = blockIdx.x;
    const int t = threadIdx.x;
    if (b < 8192) {
        // ---- gate: one wave per row, 4 rows per block, pure streaming ----
        const int lane = t & 63, wid = t >> 6;
        const int row = b * 4 + wid;
        const float* xr = x + (size_t)row * DIM;
        float acc = 0.f;
#pragma unroll
        for (int i = 0; i < 8; ++i) {
            const int c = i * 256 + lane * 4;
            f32x4 a = __builtin_nontemporal_load((const f32x4*)&xr[c]);
            f32x4 w = *(const f32x4*)&Wg[c];
#pragma unroll
            for (int j = 0; j < 4; ++j) acc = fmaf(a[j], w[j], acc);
        }
#pragma unroll
        for (int off = 32; off >= 1; off >>= 1) acc += __shfl_down(acc, off);
        if (lane == 0) scores[row] = acc + bg[0];
    } else {
        // ---- convert + transpose W (f32 [k][n] -> bf16 [n][k]) ----
        const int cb = b - 8192;
        const int z = cb >> 10;            // 0: W1, 1: W2
        const int rem = cb & 1023;
        const int k0 = (rem & 31) * 64;
        const int n0 = (rem >> 5) * 64;
        const float* W = z ? W2 : W1;
        unsigned short* Wt = z ? W2t : W1t;
        {
            const int r = t >> 4, c = (t & 15) * 4;
#pragma unroll
            for (int p = 0; p < 4; ++p) {
                const int rr = p * 16 + r;
                f32x4 v = *(const f32x4*)&W[(size_t)(k0 + rr) * DIM + n0 + c];
#pragma unroll
                for (int j = 0; j < 4; ++j) tile[rr][c + j] = f2bf(v[j]);
            }
        }
        __syncthreads();
        {
            const int n = t >> 4, kk = (t & 15) * 4;
#pragma unroll
            for (int p = 0; p < 4; ++p) {
                const int nn = p * 16 + n;
                us4 o;
#pragma unroll
                for (int j = 0; j < 4; ++j) o[j] = tile[kk + j][nn];
                *(us4*)&Wt[(size_t)(n0 + nn) * DIM + k0 + kk] = o;
            }
        }
    }
}

// ---------------- top-K select (block 0) + partial out zero + mask ----
// Block 0: single-block bisection select (~11 us). Blocks 1..768 zero
// out rows [0, SELZR) (100.7 MB ~= 15 us -> select fully hidden).
// Block 769 zeroes mask (gather then sets the KSEL ones).
__global__ __launch_bounds__(1024) void selzero_k(const float* __restrict__ scores,
                                                  int* __restrict__ sel,
                                                  float* __restrict__ outbuf) {
    const int t = threadIdx.x;
    if (blockIdx.x > 0) {
        const f32x4 zf = {};
        const int zb = blockIdx.x - 1;
        if (zb < 768) {
            // ---- zero-stream role: 128 KiB per block ----
            f32x4* p = (f32x4*)outbuf + (size_t)zb * 8192 + t;
#pragma unroll
            for (int r = 0; r < 8; ++r)
                __builtin_nontemporal_store(zf, p + r * 1024);
        } else {
            // ---- mask zero: 32768 floats ----
            f32x4* p = (f32x4*)(outbuf + (size_t)N_ROWS * DIM) + t * 2;
            __builtin_nontemporal_store(zf, p);
            __builtin_nontemporal_store(zf, p + 1);
        }
        return;
    }
    const int lane = t & 63, wid = t >> 6;
    unsigned key[32];
    unsigned kmin = 0xFFFFFFFFu, kmax = 0u;
#pragma unroll
    for (int i = 0; i < 8; ++i) {
        f32x4 v = *(const f32x4*)&scores[t * 32 + i * 4];
#pragma unroll
        for (int j = 0; j < 4; ++j) {
            unsigned u = __float_as_uint(v[j]);
            u = (u & 0x80000000u) ? ~u : (u | 0x80000000u);
            key[i * 4 + j] = u;
            kmin = min(kmin, u);
            kmax = max(kmax, u);
        }
    }
#pragma unroll
    for (int off = 32; off >= 1; off >>= 1) {
        kmin = min(kmin, (unsigned)__shfl_down((int)kmin, off));
        kmax = max(kmax, (unsigned)__shfl_down((int)kmax, off));
    }
    __shared__ unsigned wmin[16], wmax[16];
    __shared__ unsigned cnt[40];
    __shared__ unsigned gmin, gmax;
    if (t < 40) cnt[t] = 0u;
    if (lane == 0) { wmin[wid] = kmin; wmax[wid] = kmax; }
    __syncthreads();
    if (t == 0) {
        unsigned mn = wmin[0], mx = wmax[0];
        for (int w = 1; w < 16; ++w) { mn = min(mn, wmin[w]); mx = max(mx, wmax[w]); }
        gmin = mn; gmax = mx;
    }
    __syncthreads();
    unsigned lo = gmin, hi = gmax;
    int it = 0;
    while (lo < hi) {
        const unsigned mid = (unsigned)(((unsigned long long)lo + hi + 1ull) >> 1);
        int c = 0;
#pragma unroll
        for (int i = 0; i < 32; ++i) c += (key[i] >= mid) ? 1 : 0;
#pragma unroll
        for (int off = 32; off >= 1; off >>= 1) c += __shfl_down(c, off);
        if (lane == 0) atomicAdd(&cnt[it], (unsigned)c);
        __syncthreads();
        const unsigned total = cnt[it];
        if (total >= (unsigned)KSEL) lo = mid; else hi = mid - 1;
        ++it;   // fresh counter slot each iter -> one barrier per iter
    }
    const unsigned kv = lo;   // K-th largest key
    __shared__ unsigned ctr, ectr;
    __shared__ int eq[256];
    if (t == 0) { ctr = 0; ectr = 0; }
    __syncthreads();
#pragma unroll
    for (int i = 0; i < 32; ++i) {
        const unsigned k = key[i];
        if (k > kv) {
            unsigned p = atomicAdd(&ctr, 1u);
            sel[p] = t * 32 + i;
        } else if (k == kv) {
            unsigned p = atomicAdd(&ectr, 1u);
            if (p < 256u) eq[p] = t * 32 + i;
        }
    }
    __syncthreads();
    if (t == 0) {   // ties at kv: take smallest indices (lax.top_k stability)
        const int C = (int)ctr;
        const int R = KSEL - C;
        const int E = (int)(ectr < 256u ? ectr : 256u);
        for (int r = 0; r < R; ++r) {
            int mi = r;
            for (int j = r + 1; j < E; ++j)
                if (eq[j] < eq[mi]) mi = j;
            int tmp = eq[r]; eq[r] = eq[mi]; eq[mi] = tmp;
            sel[C + r] = eq[r];
        }
    }
}

// ---------------- gather active rows -> bf16 A, write mask ------------
__global__ __launch_bounds__(256) void gather_k(const float* __restrict__ x,
                                                const int* __restrict__ sel,
                                                unsigned short* __restrict__ Abf,
                                                float* __restrict__ mask) {
    const int b = blockIdx.x, t = threadIdx.x;
    unsigned short* dst = Abf + (size_t)b * DIM + t * 8;
    if (b < KSEL) {
        const int src = sel[b];
        if (t == 0) mask[src] = 1.0f;
        const float* xr = x + (size_t)src * DIM + t * 8;
        f32x4 v0 = *(const f32x4*)xr;
        f32x4 v1 = *(const f32x4*)(xr + 4);
        us8 o;
#pragma unroll
        for (int j = 0; j < 4; ++j) { o[j] = f2bf(v0[j]); o[j + 4] = f2bf(v1[j]); }
        *(us8*)dst = o;
    } else {
        us8 z = {};
        *(us8*)dst = z;   // zero pad rows so GEMM tiles are full
    }
}

// ---------------- GEMM: C[MPAD x DIM] = A[MPAD x DIM] * Bt^T ----------
// 128x64 tile, BK=64, 4 waves (2Mx2N, 64x32 each), 16x16x32 bf16 MFMA.
// LDS 48 KB/block, blocks 0..415 = compute (XOR-swizzled both-sides LDS,
// bijective XCD swizzle: 416 = 8x52). Blocks 416..735 = TAIL zero-stream
// role: 32 out-rows each, retiring the poisoned-out zeroing under the
// GEMM's spare HBM BW (~4.5 TB/s headroom over the MFMA window). Tail
// blocks dispatch after all 416 compute blocks -> no residency
// displacement (R2 lesson).
// EPI=0: H = relu(A*W1+b1) -> bf16; tail zeroes rows [SELZR, G0ZR)
//        unconditionally (gemm1's later scatter overwrites selected).
// EPI=1: scatter f32 rows of A*W2+b2; tail zeroes rows [G0ZR, N_ROWS)
//        mask-conditionally (skips selected -> disjoint from scatter).
template <int EPI>
__global__ __launch_bounds__(256, 2) void gemm_k(const unsigned short* __restrict__ A,
                                                 const unsigned short* __restrict__ Bt,
                                                 const float* __restrict__ bias,
                                                 unsigned short* __restrict__ Hout,
                                                 float* __restrict__ Cout,
                                                 const int* __restrict__ sel,
                                                 const float* __restrict__ mask,
                                                 float* __restrict__ zout) {
    __shared__ unsigned short lA[2][128 * 64];
    __shared__ unsigned short lB[2][64 * 64];
    const int t = threadIdx.x;

    if (blockIdx.x >= GTILE) {
        // ---- tail zero-stream role: 32 rows x 8 KB ----
        const int zb = blockIdx.x - GTILE;
        const int row0 = (EPI ? G0ZR : SELZR) + zb * 32;
        const f32x4 zf = {};
        f32x4* base = (f32x4*)(zout + (size_t)row0 * DIM) + t;
        for (int r = 0; r < 32; ++r) {
            if (EPI == 1) {
                // same-address wave read -> broadcast; selected rows are
                // the scatter's (this launch) -> skip, race-free
                if (__float_as_uint(mask[row0 + r]) != 0u) continue;
            }
            f32x4* p = base + r * 512;
            __builtin_nontemporal_store(zf, p);
            __builtin_nontemporal_store(zf, p + 256);
        }
        return;
    }

    const int lane = t & 63;
    const int wid = t >> 6;
    const int swz = (blockIdx.x & 7) * 52 + (blockIdx.x >> 3);
    const int m0 = (swz % 13) * 128;
    const int n0 = (swz / 13) * 64;
    const int wm = (wid >> 1) * 64;
    const int wn = (wid & 1) * 32;

    f32x4 acc[4][2] = {};

    // staging: A tile 128x64 = 1024 16B chunks (4/thread), B 64x64 = 512 (2/thread)
    const unsigned short *gA[4], *gB[2];
    int la[4], lb[2];
#pragma unroll
    for (int i = 0; i < 4; ++i) {
        const int e = t + i * 256, r = e >> 3;
        gA[i] = A + (size_t)(m0 + r) * DIM + ((e & 7) ^ (r & 7)) * 8;
        la[i] = e * 8;
    }
#pragma unroll
    for (int i = 0; i < 2; ++i) {
        const int e = t + i * 256, r = e >> 3;
        gB[i] = Bt + (size_t)(n0 + r) * DIM + ((e & 7) ^ (r & 7)) * 8;
        lb[i] = e * 8;
    }

    // fragment read offsets (shorts); physical chunk = logical ^ (lane&7)
    const int pc0 = (((lane >> 4) + 0) ^ (lane & 7)) * 8;
    const int pc1 = (((lane >> 4) + 4) ^ (lane & 7)) * 8;
    const int aob = (wm + (lane & 15)) * 64;
    const int bob = (wn + (lane & 15)) * 64;

    // prologue: stage k=0 into buf 0
#pragma unroll
    for (int i = 0; i < 4; ++i) gload_lds16(gA[i], &lA[0][la[i]]);
#pragma unroll
    for (int i = 0; i < 2; ++i) gload_lds16(gB[i], &lB[0][lb[i]]);
    __syncthreads();

    int cur = 0;
    for (int k0 = 0; k0 < DIM; k0 += 64) {
        if (k0 + 64 < DIM) {   // issue next tile's loads before compute
            const int nxt = cur ^ 1, kn = k0 + 64;
#pragma unroll
            for (int i = 0; i < 4; ++i) gload_lds16(gA[i] + kn, &lA[nxt][la[i]]);
#pragma unroll
            for (int i = 0; i < 2; ++i) gload_lds16(gB[i] + kn, &lB[nxt][lb[i]]);
        }
        bf16x8 af0[4], af1[4], bf0[2], bf1[2];
#pragma unroll
        for (int mf = 0; mf < 4; ++mf) {
            af0[mf] = *(const bf16x8*)&lA[cur][aob + mf * 1024 + pc0];
            af1[mf] = *(const bf16x8*)&lA[cur][aob + mf * 1024 + pc1];
        }
#pragma unroll
        for (int nf = 0; nf < 2; ++nf) {
            bf0[nf] = *(const bf16x8*)&lB[cur][bob + nf * 1024 + pc0];
            bf1[nf] = *(const bf16x8*)&lB[cur][bob + nf * 1024 + pc1];
        }
#pragma unroll
        for (int mf = 0; mf < 4; ++mf)
#pragma unroll
            for (int nf = 0; nf < 2; ++nf)
                acc[mf][nf] = __builtin_amdgcn_mfma_f32_16x16x32_bf16(
                    af0[mf], bf0[nf], acc[mf][nf], 0, 0, 0);
#pragma unroll
        for (int mf = 0; mf < 4; ++mf)
#pragma unroll
            for (int nf = 0; nf < 2; ++nf)
                acc[mf][nf] = __builtin_amdgcn_mfma_f32_16x16x32_bf16(
                    af1[mf], bf1[nf], acc[mf][nf], 0, 0, 0);
        __syncthreads();   // drains vmcnt(0): next buffer ready, prev reads done
        cur ^= 1;
    }

#pragma unroll
    for (int mf = 0; mf < 4; ++mf) {
        const int rbase = m0 + wm + mf * 16 + (lane >> 4) * 4;
#pragma unroll
        for (int nf = 0; nf < 2; ++nf) {
            const int col = n0 + wn + nf * 16 + (lane & 15);
            const float bv = bias[col];
            if (EPI == 0) {
#pragma unroll
                for (int j = 0; j < 4; ++j) {
                    float v = acc[mf][nf][j] + bv;
                    v = fmaxf(v, 0.f);
                    Hout[(size_t)(rbase + j) * DIM + col] = f2bf(v);
                }
            } else {
#pragma unroll
                for (int j = 0; j < 4; ++j) {
                    const int r = rbase + j;
                    if (r < KSEL) {
                        __builtin_nontemporal_store(
                            acc[mf][nf][j] + bv,
                            &Cout[(size_t)sel[r] * DIM + col]);
                    }
                }
            }
        }
    }
}

extern "C" void kernel_launch(void* const* d_in, const int* in_sizes, int n_in,
                              void* d_out, int out_size, void* d_ws, size_t ws_size,
                              hipStream_t stream) {
    const float* x  = (const float*)d_in[0];
    const float* W1 = (const float*)d_in[1];
    const float* b1 = (const float*)d_in[2];
    const float* W2 = (const float*)d_in[3];
    const float* b2 = (const float*)d_in[4];
    const float* Wg = (const float*)d_in[5];
    const float* bg = (const float*)d_in[6];
    float* out  = (float*)d_out;
    float* mask = out + (size_t)N_ROWS * DIM;

    char* w = (char*)d_ws;
    float* scores = (float*)w;           w += (size_t)N_ROWS * 4;
    int* sel = (int*)w;                  w += 2048 * 4;
    unsigned short* Abf = (unsigned short*)w;  w += (size_t)MPAD * DIM * 2;
    unsigned short* Hbf = (unsigned short*)w;  w += (size_t)MPAD * DIM * 2;
    unsigned short* W1t = (unsigned short*)w;  w += (size_t)DIM * DIM * 2;
    unsigned short* W2t = (unsigned short*)w;  w += (size_t)DIM * DIM * 2;

    // pure read streams: gate dot-products + W convert/transpose
    hipLaunchKernelGGL(prep_k, dim3(8192 + 2048), dim3(256), 0, stream,
                       x, Wg, bg, scores, W1, W2, W1t, W2t);
    // block 0: top-K select; blocks 1..768: zero out rows [0,SELZR);
    // block 769: zero mask. Select hidden under ~15 us of zero stream.
    hipLaunchKernelGGL(selzero_k, dim3(770), dim3(1024), 0, stream,
                       scores, sel, out);
    hipLaunchKernelGGL(gather_k, dim3(MPAD), dim3(256), 0, stream, x, sel, Abf, mask);
    // 416 compute blocks + 320 tail zero blocks each
    hipLaunchKernelGGL((gemm_k<0>), dim3(GTILE + ZTAIL), dim3(256), 0, stream,
                       Abf, W1t, b1, Hbf, (float*)nullptr, (const int*)nullptr,
                       mask, out);
    hipLaunchKernelGGL((gemm_k<1>), dim3(GTILE + ZTAIL), dim3(256), 0, stream,
                       Hbf, W2t, b2, (unsigned short*)nullptr, out, sel,
                       mask, out);
}

// Round 6
// 144.836 us; speedup vs baseline: 1.3471x; 1.0252x over previous
//
#include <hip/hip_runtime.h>

#define N_ROWS 32768
#define DIM    2048
#define KSEL   1638
#define MPAD   1664   // KSEL padded to multiple of 128
#define GTILE  416    // 13 x 32 gemm tiles
#define SELZR  12800  // rows zeroed in selzero_k (800 blocks x 16 rows)
#define G0Z0   12800  // gemm0 in-loop zeroes [12800, 26112)  (416 x 32 rows)
#define G1Z0   26112  // gemm1 in-loop zeroes [26112, 32768)  (416 x 16 rows)

typedef __attribute__((ext_vector_type(4))) float          f32x4;
typedef __attribute__((ext_vector_type(4))) unsigned short us4;
typedef __attribute__((ext_vector_type(8))) unsigned short us8;
typedef __bf16 bf16x8 __attribute__((ext_vector_type(8)));

__device__ __forceinline__ unsigned short f2bf(float f) {
    unsigned u = __float_as_uint(f);
    u += 0x7FFFu + ((u >> 16) & 1u);   // RNE
    return (unsigned short)(u >> 16);
}

__device__ __forceinline__ void gload_lds16(const void* g, void* l) {
    __builtin_amdgcn_global_load_lds(
        (const __attribute__((address_space(1))) unsigned int*)(uintptr_t)g,
        (__attribute__((address_space(3))) unsigned int*)(uintptr_t)l, 16, 0, 0);
}

// ---------------- prep: gate dot-products + W transpose/convert -------
// Pure read streams (268 MB x + 50 MB W). The mandatory 268 MB out-zero
// (harness re-poisons out every iteration) is split: 105 MB in selzero_k
// (hides the single-block select), 109/55 MB issued IN-LOOP by the GEMM
// compute blocks under counted vmcnt (R5 lesson: tail/dedicated zero
// blocks are CU-issue-limited to ~26 GB/s/CU -- only stores issued from
// ALL 416 compute blocks spread thin enough to hide).
__global__ __launch_bounds__(256) void prep_k(const float* __restrict__ x,
                                              const float* __restrict__ Wg,
                                              const float* __restrict__ bg,
                                              float* __restrict__ scores,
                                              const float* __restrict__ W1,
                                              const float* __restrict__ W2,
                                              unsigned short* __restrict__ W1t,
                                              unsigned short* __restrict__ W2t) {
    __shared__ unsigned short tile[64][72];   // +8 pad: conflict-free transpose
    const int b = blockIdx.x;
    const int t = threadIdx.x;
    if (b < 8192) {
        // ---- gate: one wave per row, 4 rows per block, pure streaming ----
        const int lane = t & 63, wid = t >> 6;
        const int row = b * 4 + wid;
        const float* xr = x + (size_t)row * DIM;
        float acc = 0.f;
#pragma unroll
        for (int i = 0; i < 8; ++i) {
            const int c = i * 256 + lane * 4;
            f32x4 a = __builtin_nontemporal_load((const f32x4*)&xr[c]);
            f32x4 w = *(const f32x4*)&Wg[c];
#pragma unroll
            for (int j = 0; j < 4; ++j) acc = fmaf(a[j], w[j], acc);
        }
#pragma unroll
        for (int off = 32; off >= 1; off >>= 1) acc += __shfl_down(acc, off);
        if (lane == 0) scores[row] = acc + bg[0];
    } else {
        // ---- convert + transpose W (f32 [k][n] -> bf16 [n][k]) ----
        const int cb = b - 8192;
        const int z = cb >> 10;            // 0: W1, 1: W2
        const int rem = cb & 1023;
        const int k0 = (rem & 31) * 64;
        const int n0 = (rem >> 5) * 64;
        const float* W = z ? W2 : W1;
        unsigned short* Wt = z ? W2t : W1t;
        {
            const int r = t >> 4, c = (t & 15) * 4;
#pragma unroll
            for (int p = 0; p < 4; ++p) {
                const int rr = p * 16 + r;
                f32x4 v = *(const f32x4*)&W[(size_t)(k0 + rr) * DIM + n0 + c];
#pragma unroll
                for (int j = 0; j < 4; ++j) tile[rr][c + j] = f2bf(v[j]);
            }
        }
        __syncthreads();
        {
            const int n = t >> 4, kk = (t & 15) * 4;
#pragma unroll
            for (int p = 0; p < 4; ++p) {
                const int nn = p * 16 + n;
                us4 o;
#pragma unroll
                for (int j = 0; j < 4; ++j) o[j] = tile[kk + j][nn];
                *(us4*)&Wt[(size_t)(n0 + nn) * DIM + k0 + kk] = o;
            }
        }
    }
}

// ---------------- top-K select (block 0) + partial out zero + mask ----
// Block 0: single-block bisection select (~11 us). Blocks 1..800 zero
// out rows [0, SELZR) (105 MB ~= 15 us -> select fully hidden).
// Block 801 zeroes mask (gather then sets the KSEL ones).
__global__ __launch_bounds__(1024) void selzero_k(const float* __restrict__ scores,
                                                  int* __restrict__ sel,
                                                  float* __restrict__ outbuf) {
    const int t = threadIdx.x;
    if (blockIdx.x > 0) {
        const f32x4 zf = {};
        const int zb = blockIdx.x - 1;
        if (zb < 800) {
            // ---- zero-stream role: 128 KiB (16 rows) per block ----
            f32x4* p = (f32x4*)outbuf + (size_t)zb * 8192 + t;
#pragma unroll
            for (int r = 0; r < 8; ++r)
                __builtin_nontemporal_store(zf, p + r * 1024);
        } else {
            // ---- mask zero: 32768 floats ----
            f32x4* p = (f32x4*)(outbuf + (size_t)N_ROWS * DIM) + t * 2;
            __builtin_nontemporal_store(zf, p);
            __builtin_nontemporal_store(zf, p + 1);
        }
        return;
    }
    const int lane = t & 63, wid = t >> 6;
    unsigned key[32];
    unsigned kmin = 0xFFFFFFFFu, kmax = 0u;
#pragma unroll
    for (int i = 0; i < 8; ++i) {
        f32x4 v = *(const f32x4*)&scores[t * 32 + i * 4];
#pragma unroll
        for (int j = 0; j < 4; ++j) {
            unsigned u = __float_as_uint(v[j]);
            u = (u & 0x80000000u) ? ~u : (u | 0x80000000u);
            key[i * 4 + j] = u;
            kmin = min(kmin, u);
            kmax = max(kmax, u);
        }
    }
#pragma unroll
    for (int off = 32; off >= 1; off >>= 1) {
        kmin = min(kmin, (unsigned)__shfl_down((int)kmin, off));
        kmax = max(kmax, (unsigned)__shfl_down((int)kmax, off));
    }
    __shared__ unsigned wmin[16], wmax[16];
    __shared__ unsigned cnt[40];
    __shared__ unsigned gmin, gmax;
    if (t < 40) cnt[t] = 0u;
    if (lane == 0) { wmin[wid] = kmin; wmax[wid] = kmax; }
    __syncthreads();
    if (t == 0) {
        unsigned mn = wmin[0], mx = wmax[0];
        for (int w = 1; w < 16; ++w) { mn = min(mn, wmin[w]); mx = max(mx, wmax[w]); }
        gmin = mn; gmax = mx;
    }
    __syncthreads();
    unsigned lo = gmin, hi = gmax;
    int it = 0;
    while (lo < hi) {
        const unsigned mid = (unsigned)(((unsigned long long)lo + hi + 1ull) >> 1);
        int c = 0;
#pragma unroll
        for (int i = 0; i < 32; ++i) c += (key[i] >= mid) ? 1 : 0;
#pragma unroll
        for (int off = 32; off >= 1; off >>= 1) c += __shfl_down(c, off);
        if (lane == 0) atomicAdd(&cnt[it], (unsigned)c);
        __syncthreads();
        const unsigned total = cnt[it];
        if (total >= (unsigned)KSEL) lo = mid; else hi = mid - 1;
        ++it;   // fresh counter slot each iter -> one barrier per iter
    }
    const unsigned kv = lo;   // K-th largest key
    __shared__ unsigned ctr, ectr;
    __shared__ int eq[256];
    if (t == 0) { ctr = 0; ectr = 0; }
    __syncthreads();
#pragma unroll
    for (int i = 0; i < 32; ++i) {
        const unsigned k = key[i];
        if (k > kv) {
            unsigned p = atomicAdd(&ctr, 1u);
            sel[p] = t * 32 + i;
        } else if (k == kv) {
            unsigned p = atomicAdd(&ectr, 1u);
            if (p < 256u) eq[p] = t * 32 + i;
        }
    }
    __syncthreads();
    if (t == 0) {   // ties at kv: take smallest indices (lax.top_k stability)
        const int C = (int)ctr;
        const int R = KSEL - C;
        const int E = (int)(ectr < 256u ? ectr : 256u);
        for (int r = 0; r < R; ++r) {
            int mi = r;
            for (int j = r + 1; j < E; ++j)
                if (eq[j] < eq[mi]) mi = j;
            int tmp = eq[r]; eq[r] = eq[mi]; eq[mi] = tmp;
            sel[C + r] = eq[r];
        }
    }
}

// ---------------- gather active rows -> bf16 A, write mask ------------
__global__ __launch_bounds__(256) void gather_k(const float* __restrict__ x,
                                                const int* __restrict__ sel,
                                                unsigned short* __restrict__ Abf,
                                                float* __restrict__ mask) {
    const int b = blockIdx.x, t = threadIdx.x;
    unsigned short* dst = Abf + (size_t)b * DIM + t * 8;
    if (b < KSEL) {
        const int src = sel[b];
        if (t == 0) mask[src] = 1.0f;
        const float* xr = x + (size_t)src * DIM + t * 8;
        f32x4 v0 = *(const f32x4*)xr;
        f32x4 v1 = *(const f32x4*)(xr + 4);
        us8 o;
#pragma unroll
        for (int j = 0; j < 4; ++j) { o[j] = f2bf(v0[j]); o[j + 4] = f2bf(v1[j]); }
        *(us8*)dst = o;
    } else {
        us8 z = {};
        *(us8*)dst = z;   // zero pad rows so GEMM tiles are full
    }
}

// ---------------- GEMM: C[MPAD x DIM] = A[MPAD x DIM] * Bt^T ----------
// 128x64 tile, BK=64, 4 waves (2Mx2N), 16x16x32 bf16 MFMA, LDS 48 KB,
// 2 blocks/CU, XOR-swizzled both-sides LDS, bijective XCD swizzle.
// Fused out-zero with COUNTED vmcnt (T4): per iteration the block issues
// its zero-stores AFTER the 6 staging gload_lds, then waits
// s_waitcnt vmcnt(#stores) before a raw s_barrier -- staging loads
// (older) are forced complete, the newest stores stay in flight with a
// full iteration to retire under the MFMA stream. This is R1's placement
// with the vmcnt(0)-drain removed (the R1 failure mode), and spreads the
// stores across all 416 blocks/208 CUs (the R5 failure mode was zeroing
// from only 48 CUs at ~26 GB/s/CU).
// Ordering (rule 18): memory-clobber asm before the barrier; empty
// memory-clobber asm + sched_barrier(0) after it so next-iter LDS reads
// cannot hoist above the rendezvous.
// EPI=0: H = relu(A*W1+b1) -> bf16; zeroes rows [G0Z0, G1Z0)
//        unconditionally (gemm1's later scatter overwrites selected).
// EPI=1: scatter f32 rows of A*W2+b2; zeroes rows [G1Z0, N_ROWS)
//        mask-checked via LDS smask (disjoint from its own scatter).
template <int EPI>
__global__ __launch_bounds__(256, 2) void gemm_k(const unsigned short* __restrict__ A,
                                                 const unsigned short* __restrict__ Bt,
                                                 const float* __restrict__ bias,
                                                 unsigned short* __restrict__ Hout,
                                                 float* __restrict__ Cout,
                                                 const int* __restrict__ sel,
                                                 const float* __restrict__ mask,
                                                 float* __restrict__ zout) {
    __shared__ unsigned short lA[2][128 * 64];
    __shared__ unsigned short lB[2][64 * 64];
    __shared__ float smask[16];
    const int t = threadIdx.x;
    const int lane = t & 63;
    const int wid = t >> 6;
    const int bid = blockIdx.x;
    const int swz = (bid & 7) * 52 + (bid >> 3);
    const int m0 = (swz % 13) * 128;
    const int n0 = (swz / 13) * 64;
    const int wm = (wid >> 1) * 64;
    const int wn = (wid & 1) * 32;

    // zero-offload setup: contiguous region per block, pointer-bump rounds
    const int zrow0 = EPI ? (G1Z0 + bid * 16) : (G0Z0 + bid * 32);
    float* zptr = zout + (size_t)zrow0 * DIM + t * 4;
    if (EPI == 1 && t < 16) smask[t] = mask[zrow0 + t];

    f32x4 acc[4][2] = {};

    // staging: A tile 128x64 = 1024 16B chunks (4/thread), B 64x64 = 512 (2/thread)
    const unsigned short *gA[4], *gB[2];
    int la[4], lb[2];
#pragma unroll
    for (int i = 0; i < 4; ++i) {
        const int e = t + i * 256, r = e >> 3;
        gA[i] = A + (size_t)(m0 + r) * DIM + ((e & 7) ^ (r & 7)) * 8;
        la[i] = e * 8;
    }
#pragma unroll
    for (int i = 0; i < 2; ++i) {
        const int e = t + i * 256, r = e >> 3;
        gB[i] = Bt + (size_t)(n0 + r) * DIM + ((e & 7) ^ (r & 7)) * 8;
        lb[i] = e * 8;
    }

    // fragment read offsets (shorts); physical chunk = logical ^ (lane&7)
    const int pc0 = (((lane >> 4) + 0) ^ (lane & 7)) * 8;
    const int pc1 = (((lane >> 4) + 4) ^ (lane & 7)) * 8;
    const int aob = (wm + (lane & 15)) * 64;
    const int bob = (wn + (lane & 15)) * 64;

    // prologue: stage k=0 into buf 0 (smask write covered by this barrier)
#pragma unroll
    for (int i = 0; i < 4; ++i) gload_lds16(gA[i], &lA[0][la[i]]);
#pragma unroll
    for (int i = 0; i < 2; ++i) gload_lds16(gB[i], &lB[0][lb[i]]);
    __syncthreads();

    const f32x4 zf = {};
    int cur = 0;
    for (int k0 = 0; k0 < DIM; k0 += 64) {
        if (k0 + 64 < DIM) {   // issue next tile's loads before compute
            const int nxt = cur ^ 1, kn = k0 + 64;
#pragma unroll
            for (int i = 0; i < 4; ++i) gload_lds16(gA[i] + kn, &lA[nxt][la[i]]);
#pragma unroll
            for (int i = 0; i < 2; ++i) gload_lds16(gB[i] + kn, &lB[nxt][lb[i]]);
        }
        // fused out-zero rounds (4 KB each, contiguous; issued AFTER the
        // staging loads so counted vmcnt leaves only these in flight)
        if (EPI == 0) {
            __builtin_nontemporal_store(zf, (f32x4*)zptr);
            __builtin_nontemporal_store(zf, (f32x4*)zptr + 256);
            zptr += 2048;
        } else {
            if (__float_as_uint(smask[k0 >> 7]) == 0u)
                __builtin_nontemporal_store(zf, (f32x4*)zptr);
            zptr += 1024;
        }
        bf16x8 af0[4], af1[4], bf0[2], bf1[2];
#pragma unroll
        for (int mf = 0; mf < 4; ++mf) {
            af0[mf] = *(const bf16x8*)&lA[cur][aob + mf * 1024 + pc0];
            af1[mf] = *(const bf16x8*)&lA[cur][aob + mf * 1024 + pc1];
        }
#pragma unroll
        for (int nf = 0; nf < 2; ++nf) {
            bf0[nf] = *(const bf16x8*)&lB[cur][bob + nf * 1024 + pc0];
            bf1[nf] = *(const bf16x8*)&lB[cur][bob + nf * 1024 + pc1];
        }
#pragma unroll
        for (int mf = 0; mf < 4; ++mf)
#pragma unroll
            for (int nf = 0; nf < 2; ++nf)
                acc[mf][nf] = __builtin_amdgcn_mfma_f32_16x16x32_bf16(
                    af0[mf], bf0[nf], acc[mf][nf], 0, 0, 0);
#pragma unroll
        for (int mf = 0; mf < 4; ++mf)
#pragma unroll
            for (int nf = 0; nf < 2; ++nf)
                acc[mf][nf] = __builtin_amdgcn_mfma_f32_16x16x32_bf16(
                    af1[mf], bf1[nf], acc[mf][nf], 0, 0, 0);
        // counted-vmcnt barrier: staging loads (older than the zero
        // stores) must be complete; the newest stores stay in flight.
        if (EPI == 0) { asm volatile("s_waitcnt vmcnt(2)" ::: "memory"); }
        else          { asm volatile("s_waitcnt vmcnt(1)" ::: "memory"); }
        __builtin_amdgcn_s_barrier();
        asm volatile("" ::: "memory");
        __builtin_amdgcn_sched_barrier(0);
        cur ^= 1;
    }

#pragma unroll
    for (int mf = 0; mf < 4; ++mf) {
        const int rbase = m0 + wm + mf * 16 + (lane >> 4) * 4;
#pragma unroll
        for (int nf = 0; nf < 2; ++nf) {
            const int col = n0 + wn + nf * 16 + (lane & 15);
            const float bv = bias[col];
            if (EPI == 0) {
#pragma unroll
                for (int j = 0; j < 4; ++j) {
                    float v = acc[mf][nf][j] + bv;
                    v = fmaxf(v, 0.f);
                    Hout[(size_t)(rbase + j) * DIM + col] = f2bf(v);
                }
            } else {
#pragma unroll
                for (int j = 0; j < 4; ++j) {
                    const int r = rbase + j;
                    if (r < KSEL) {
                        __builtin_nontemporal_store(
                            acc[mf][nf][j] + bv,
                            &Cout[(size_t)sel[r] * DIM + col]);
                    }
                }
            }
        }
    }
}

extern "C" void kernel_launch(void* const* d_in, const int* in_sizes, int n_in,
                              void* d_out, int out_size, void* d_ws, size_t ws_size,
                              hipStream_t stream) {
    const float* x  = (const float*)d_in[0];
    const float* W1 = (const float*)d_in[1];
    const float* b1 = (const float*)d_in[2];
    const float* W2 = (const float*)d_in[3];
    const float* b2 = (const float*)d_in[4];
    const float* Wg = (const float*)d_in[5];
    const float* bg = (const float*)d_in[6];
    float* out  = (float*)d_out;
    float* mask = out + (size_t)N_ROWS * DIM;

    char* w = (char*)d_ws;
    float* scores = (float*)w;           w += (size_t)N_ROWS * 4;
    int* sel = (int*)w;                  w += 2048 * 4;
    unsigned short* Abf = (unsigned short*)w;  w += (size_t)MPAD * DIM * 2;
    unsigned short* Hbf = (unsigned short*)w;  w += (size_t)MPAD * DIM * 2;
    unsigned short* W1t = (unsigned short*)w;  w += (size_t)DIM * DIM * 2;
    unsigned short* W2t = (unsigned short*)w;  w += (size_t)DIM * DIM * 2;

    // pure read streams: gate dot-products + W convert/transpose
    hipLaunchKernelGGL(prep_k, dim3(8192 + 2048), dim3(256), 0, stream,
                       x, Wg, bg, scores, W1, W2, W1t, W2t);
    // block 0: top-K select; blocks 1..800: zero out rows [0,SELZR);
    // block 801: zero mask. Select hidden under ~15 us of zero stream.
    hipLaunchKernelGGL(selzero_k, dim3(802), dim3(1024), 0, stream,
                       scores, sel, out);
    hipLaunchKernelGGL(gather_k, dim3(MPAD), dim3(256), 0, stream, x, sel, Abf, mask);
    // compute blocks carry the remaining out-zero in-loop (counted vmcnt)
    hipLaunchKernelGGL((gemm_k<0>), dim3(GTILE), dim3(256), 0, stream,
                       Abf, W1t, b1, Hbf, (float*)nullptr, (const int*)nullptr,
                       mask, out);
    hipLaunchKernelGGL((gemm_k<1>), dim3(GTILE), dim3(256), 0, stream,
                       Hbf, W2t, b2, (unsigned short*)nullptr, out, sel,
                       mask, out);
}